// Round 8
// baseline (306.488 us; speedup 1.0000x reference)
//
#include <hip/hip_runtime.h>

#define NG   256   // graphs (= grid)
#define NP   512   // nodes per graph
#define EPG  8192  // edges per graph
#define FDIM 128
#define STA  33    // bufA stride (floats): conflict-free b32 row access
#define STB  36    // bufB stride (floats): 144 B, 16B-aligned; random-row b128 spread 8 bank-groups

// ---- LDS layout (bytes) ----
#define OFF_BUFA  0                        // max(stage 65536, bufA 512*33*4=67584)
#define OFF_BUFB  67584                    // f32[512*36] -> 141312
#define OFF_CSR   141312                   // u16[8192] -> 157696
#define OFF_OFFS  157696                   // u16[513] -> 158728
#define OFF_WT    158728                   // u32[8] -> 158760
#define OFF_DCNT  158760                   // u32[512] -> 160808 (deg, cursors, lin3S)
#define OFF_NRM   160808                   // f32[512] -> 162856
#define SMEM_SZ   162856                   // <= 163840

// overlays in csr region (pre-fill: perm scratch; post key agg: sort arrays)
#define OFF_HIST OFF_CSR                   // u32[64]
#define OFF_RPRM (OFF_CSR + 256)           // u16[512]
#define OFF_KEYA OFF_CSR                   // f32[512]
#define OFF_IDXA (OFF_CSR + 2048)          // u32[512]
#define OFF_KEYB (OFF_CSR + 4096)          // f32[256]
#define OFF_IDXB (OFF_CSR + 6144)          // u32[256]
// tail arrays in bufA/stage region (float offsets)
#define FO_FEAT 0
#define FO_C1   6208
#define FO_P    7232
#define FO_C2   7744
#define FO_HID  8640

#define F4ADD(A,B) { A.x += B.x; A.y += B.y; A.z += B.z; A.w += B.w; }

__global__ __launch_bounds__(1024, 4) void dgcnn_fused(
    const float* __restrict__ x,
    const float* __restrict__ W0, const float* __restrict__ b0,
    const float* __restrict__ W1, const float* __restrict__ b1,
    const float* __restrict__ W2, const float* __restrict__ b2,
    const float* __restrict__ W3, const float* __restrict__ b3,
    const float* __restrict__ c1w, const float* __restrict__ c1b,
    const float* __restrict__ c2w, const float* __restrict__ c2b,
    const float* __restrict__ d1w, const float* __restrict__ d1b,
    const float* __restrict__ d2w, const float* __restrict__ d2b,
    const int* __restrict__ esrc, const int* __restrict__ edst,
    float* __restrict__ hs1, float* __restrict__ hs2,
    float* __restrict__ out)
{
  extern __shared__ char smem[];
  float*          stageF = (float*)(smem + OFF_BUFA);
  float*          bufA  = (float*)(smem + OFF_BUFA);
  float*          bufB  = (float*)(smem + OFF_BUFB);
  unsigned short* csr   = (unsigned short*)(smem + OFF_CSR);
  unsigned short* offs  = (unsigned short*)(smem + OFF_OFFS);
  unsigned int*   wt    = (unsigned int*)(smem + OFF_WT);
  unsigned int*   dcnt  = (unsigned int*)(smem + OFF_DCNT);
  float*          nrm   = (float*)(smem + OFF_NRM);
  float*          lin3S = (float*)(smem + OFF_DCNT);
  unsigned int*   hist  = (unsigned int*)(smem + OFF_HIST);
  unsigned short* rprm  = (unsigned short*)(smem + OFF_RPRM);
  float*          keyA  = (float*)(smem + OFF_KEYA);
  unsigned int*   idxA  = (unsigned int*)(smem + OFF_IDXA);
  float*          keyB  = (float*)(smem + OFF_KEYB);
  unsigned int*   idxB  = (unsigned int*)(smem + OFF_IDXB);

  const int g    = blockIdx.x;
  const int tid  = threadIdx.x;
  const int lane = tid & 63;
  const int wv   = __builtin_amdgcn_readfirstlane(tid >> 6);   // 0..15
  const int half = __builtin_amdgcn_readfirstlane(tid >> 9);   // 0/1
  const int hoff = half * 16;
  const int v    = tid & 511;                                  // natural node
  const int nb   = g * NP;
  const size_t gb = (size_t)g * (NP * 32);

  // x chunk staging (named regs only -> no scratch)
  const int ldRow0 = tid >> 3;
  const int ldGrp  = tid & 7;
  const int ldSwz  = (ldGrp ^ (ldRow0 & 7)) * 16;
  const float* xp0 = x + (size_t)nb * FDIM + ldGrp * 4 + (size_t)(ldRow0      ) * FDIM;
  const float* xp1 = x + (size_t)nb * FDIM + ldGrp * 4 + (size_t)(ldRow0 + 128) * FDIM;
  const float* xp2 = x + (size_t)nb * FDIM + ldGrp * 4 + (size_t)(ldRow0 + 256) * FDIM;
  const float* xp3 = x + (size_t)nb * FDIM + ldGrp * 4 + (size_t)(ldRow0 + 384) * FDIM;
  char* sp0 = smem + OFF_BUFA + (ldRow0      ) * 128 + ldSwz;
  char* sp1 = smem + OFF_BUFA + (ldRow0 + 128) * 128 + ldSwz;
  char* sp2 = smem + OFF_BUFA + (ldRow0 + 256) * 128 + ldSwz;
  char* sp3 = smem + OFF_BUFA + (ldRow0 + 384) * 128 + ldSwz;
#define LOADC(kc, r0, r1, r2, r3)                         \
  { r0 = *(const float4*)(xp0 + (kc) * 32);               \
    r1 = *(const float4*)(xp1 + (kc) * 32);               \
    r2 = *(const float4*)(xp2 + (kc) * 32);               \
    r3 = *(const float4*)(xp3 + (kc) * 32); }
#define STOREC(r0, r1, r2, r3)                            \
  { *(float4*)sp0 = r0; *(float4*)sp1 = r1;               \
    *(float4*)sp2 = r2; *(float4*)sp3 = r3; }

  float4 xA0, xA1, xA2, xA3, xB0, xB1, xB2, xB3;
  LOADC(0, xA0, xA1, xA2, xA3);

  // ---------- phase 0: zero deg counters + hist ----------
  if (tid < 512) dcnt[tid] = 0u;
  if (tid < 64)  hist[tid] = 0u;
  __syncthreads();

  // ---------- phase 1: edges via int4, packed deg counts ----------
  int es[8], ed[8];
  {
    const int eb = g * EPG;
    const int4* s4 = (const int4*)(esrc + eb);
    const int4* d4 = (const int4*)(edst + eb);
    const int4 sa = s4[tid], sb = s4[tid + 1024];
    const int4 da = d4[tid], db = d4[tid + 1024];
    es[0]=sa.x-nb; es[1]=sa.y-nb; es[2]=sa.z-nb; es[3]=sa.w-nb;
    es[4]=sb.x-nb; es[5]=sb.y-nb; es[6]=sb.z-nb; es[7]=sb.w-nb;
    ed[0]=da.x-nb; ed[1]=da.y-nb; ed[2]=da.z-nb; ed[3]=da.w-nb;
    ed[4]=db.x-nb; ed[5]=db.y-nb; ed[6]=db.z-nb; ed[7]=db.w-nb;
#pragma unroll
    for (int i = 0; i < 8; i++) {
      atomicAdd(&dcnt[es[i]], 1u);        // out-degree (low 16)
      atomicAdd(&dcnt[ed[i]], 65536u);    // in-degree  (high 16)
    }
  }
  __syncthreads();

  // ---------- phase 2: norm; scan in-degree -> offs ----------
  unsigned c_scan = 0, myindeg = 0;
  if (tid < 512) {
    const unsigned cw = dcnt[tid];
    nrm[tid] = 1.0f / (float)((cw & 0xFFFFu) + 1u);
    dcnt[tid] = 0u;                       // becomes cursor
    myindeg = cw >> 16;
    c_scan = myindeg;
    for (int d = 1; d < 64; d <<= 1) {
      const unsigned t = __shfl_up(c_scan, (unsigned)d, 64);
      if (lane >= d) c_scan += t;
    }
    if (lane == 63) wt[wv] = c_scan;
  }
  __syncthreads();
  if (tid < 512) {
    unsigned base = 0;
    for (int w = 0; w < wv; w++) base += wt[w];
    offs[tid + 1] = (unsigned short)(base + c_scan);
    if (tid == 0) offs[0] = 0;
  }

  // ---------- phase 2.5: degree-balanced permutation (counting sort) ----------
  const unsigned mybin = (myindeg > 63u) ? 63u : myindeg;
  __syncthreads();
  if (tid < 512) atomicAdd(&hist[mybin], 1u);
  __syncthreads();
  if (tid < 64) {
    const unsigned c = hist[tid];
    unsigned sc = c;
    for (int d = 1; d < 64; d <<= 1) {
      const unsigned t = __shfl_up(sc, (unsigned)d, 64);
      if (lane >= d) sc += t;
    }
    hist[tid] = sc - c;                   // exclusive prefix -> cursor
  }
  __syncthreads();
  if (tid < 512) {
    const unsigned rk = atomicAdd(&hist[mybin], 1u);
    rprm[rk] = (unsigned short)tid;
  }
  __syncthreads();
  // wave w (half0) takes rank-block w; half1 waves take mirrored blocks (SIMD spread)
  const int rblk = half ? (15 - wv) : wv;
  const int p    = (int)rprm[rblk * 64 + lane];
  __syncthreads();                        // perm scratch reads done; csr fill may overwrite

  // ---------- phase 3: fill CSR (src bucketed by dst) ----------
#pragma unroll
  for (int i = 0; i < 8; i++) {
    const unsigned pos = (unsigned)offs[ed[i]] + atomicAdd(&dcnt[ed[i]], 1u);
    csr[pos] = (unsigned short)es[i];
  }

  // ---------- phase 4: lin0 via LDS-staged x chunks ----------
  float acc0[16];
#pragma unroll
  for (int c = 0; c < 16; c++) acc0[c] = b0[hoff + c];
  const char* rowp = smem + OFF_BUFA + v * 128;
  const int vswz = v & 7;
  auto compute_chunk = [&](int kc) {
#pragma unroll
    for (int jg = 0; jg < 8; jg++) {
      const float4 t = *(const float4*)(rowp + ((jg ^ vswz) * 16));
#pragma unroll
      for (int c = 0; c < 16; c++) {
        const float* wr = W0 + (size_t)(hoff + c) * FDIM + kc * 32 + jg * 4;
        acc0[c] = fmaf(t.x, wr[0], acc0[c]);
        acc0[c] = fmaf(t.y, wr[1], acc0[c]);
        acc0[c] = fmaf(t.z, wr[2], acc0[c]);
        acc0[c] = fmaf(t.w, wr[3], acc0[c]);
      }
    }
  };
  STOREC(xA0, xA1, xA2, xA3);
  LOADC(1, xB0, xB1, xB2, xB3);
  __syncthreads();
  compute_chunk(0);
  __syncthreads();
  STOREC(xB0, xB1, xB2, xB3);
  LOADC(2, xA0, xA1, xA2, xA3);
  __syncthreads();
  compute_chunk(1);
  __syncthreads();
  STOREC(xA0, xA1, xA2, xA3);
  LOADC(3, xB0, xB1, xB2, xB3);
  __syncthreads();
  compute_chunk(2);
  __syncthreads();
  STOREC(xB0, xB1, xB2, xB3);
  __syncthreads();
  compute_chunk(3);
  {
    float4* br = (float4*)(bufB + v * STB + hoff);
#pragma unroll
    for (int j = 0; j < 4; j++)
      br[j] = make_float4(acc0[j*4+0], acc0[j*4+1], acc0[j*4+2], acc0[j*4+3]);
  }
  __syncthreads();

  // aggregate own half of node p from bufB: h = tanh(nrm*(self+sum_neigh)); 4-wide
  float h[16];
  auto do_agg = [&]() {
    const int e0 = offs[p], e1 = offs[p + 1];
    const float4* sr = (const float4*)(bufB + p * STB + hoff);
    float4 A0 = sr[0], A1 = sr[1], A2 = sr[2], A3 = sr[3];
    int e = e0;
    for (; e + 3 < e1; e += 4) {
      const int s0 = csr[e], s1 = csr[e + 1], s2 = csr[e + 2], s3 = csr[e + 3];
      const float4* r0 = (const float4*)(bufB + s0 * STB + hoff);
      const float4* r1 = (const float4*)(bufB + s1 * STB + hoff);
      const float4* r2 = (const float4*)(bufB + s2 * STB + hoff);
      const float4* r3 = (const float4*)(bufB + s3 * STB + hoff);
      float4 a0 = r0[0], a1 = r0[1], a2 = r0[2], a3 = r0[3];
      float4 b0v = r1[0], b1v = r1[1], b2v = r1[2], b3v = r1[3];
      float4 c0 = r2[0], c1 = r2[1], c2 = r2[2], c3 = r2[3];
      float4 d0 = r3[0], d1 = r3[1], d2 = r3[2], d3 = r3[3];
      F4ADD(a0, b0v) F4ADD(a1, b1v) F4ADD(a2, b2v) F4ADD(a3, b3v)
      F4ADD(c0, d0)  F4ADD(c1, d1)  F4ADD(c2, d2)  F4ADD(c3, d3)
      F4ADD(a0, c0)  F4ADD(a1, c1)  F4ADD(a2, c2)  F4ADD(a3, c3)
      F4ADD(A0, a0)  F4ADD(A1, a1)  F4ADD(A2, a2)  F4ADD(A3, a3)
    }
    for (; e < e1; e++) {
      const int s = csr[e];
      const float4* rb = (const float4*)(bufB + s * STB + hoff);
      float4 a0 = rb[0], a1 = rb[1], a2 = rb[2], a3 = rb[3];
      F4ADD(A0, a0) F4ADD(A1, a1) F4ADD(A2, a2) F4ADD(A3, a3)
    }
    const float nv = nrm[p];
    h[0]=tanhf(A0.x*nv); h[1]=tanhf(A0.y*nv); h[2]=tanhf(A0.z*nv); h[3]=tanhf(A0.w*nv);
    h[4]=tanhf(A1.x*nv); h[5]=tanhf(A1.y*nv); h[6]=tanhf(A1.z*nv); h[7]=tanhf(A1.w*nv);
    h[8]=tanhf(A2.x*nv); h[9]=tanhf(A2.y*nv); h[10]=tanhf(A2.z*nv); h[11]=tanhf(A2.w*nv);
    h[12]=tanhf(A3.x*nv); h[13]=tanhf(A3.y*nv); h[14]=tanhf(A3.z*nv); h[15]=tanhf(A3.w*nv);
  };

  // write own half of node p's h into bufA (stride 33)
  auto put_hA = [&]() {
    float* aw = bufA + p * STA + hoff;
#pragma unroll
    for (int j = 0; j < 16; j++) aw[j] = h[j];
  };

  // coalesced spill from bufA by natural node order (after barrier)
  auto spill_nat = [&](float* dst) {
    const float* ar = bufA + v * STA + hoff;
#pragma unroll
    for (int c = 0; c < 16; c++)
      dst[gb + (size_t)(hoff + c) * 512 + v] = ar[c];
  };

  // lin for node p: own half from regs + other half from bufA -> bufB row p
  auto do_lin = [&](const float* __restrict__ W, const float* __restrict__ b) {
    float hf[16];
    const float* ar = bufA + p * STA + (hoff ^ 16);
#pragma unroll
    for (int j = 0; j < 16; j++) hf[j] = ar[j];
    float acc[16];
#pragma unroll
    for (int c = 0; c < 16; c++) {
      const int C = hoff + c;
      const float* wr = W + C * 32;
      float a = b[C];
#pragma unroll
      for (int j = 0; j < 16; j++) a = fmaf(h[j],  wr[hoff + j], a);
#pragma unroll
      for (int j = 0; j < 16; j++) a = fmaf(hf[j], wr[(hoff ^ 16) + j], a);
      acc[c] = a;
    }
    float4* br = (float4*)(bufB + p * STB + hoff);
#pragma unroll
    for (int j = 0; j < 4; j++)
      br[j] = make_float4(acc[j*4+0], acc[j*4+1], acc[j*4+2], acc[j*4+3]);
  };

  // ---------- layers ----------
  do_agg();                       // h1 (reads bufB)
  put_hA();
  __syncthreads();
  spill_nat(hs1);
  do_lin(W1, b1);                 // reads bufA, writes bufB
  __syncthreads();
  do_agg();                       // h2
  put_hA();
  __syncthreads();
  spill_nat(hs2);
  do_lin(W2, b2);
  __syncthreads();
  do_agg();                       // h3
  put_hA();                       // full h3 in bufA
  __syncthreads();

  // ---------- layer 3 (1 ch, double acc — sort key) ----------
  if (tid < 512) {
    const float* ar = bufA + tid * STA;
    double a = (double)b3[0];
#pragma unroll
    for (int j = 0; j < 32; j++) a = fma((double)ar[j], (double)W3[j], a);
    lin3S[tid] = (float)a;
  }
  __syncthreads();
  float h4 = 0.f;
  if (tid < 512) {
    double a = (double)lin3S[p];
    const int e0 = offs[p], e1 = offs[p + 1];
    int e = e0;
    for (; e + 3 < e1; e += 4) {
      const int s0 = csr[e], s1 = csr[e+1], s2 = csr[e+2], s3 = csr[e+3];
      a += ((double)lin3S[s0] + (double)lin3S[s1]) + ((double)lin3S[s2] + (double)lin3S[s3]);
    }
    for (; e < e1; e++) a += (double)lin3S[csr[e]];
    a *= (double)nrm[p];
    h4 = tanhf((float)a);
  }
  __syncthreads();     // csr reads done; sort arrays may overlay csr

  // ---------- in-wave bitonic sort (desc, stable by node id) ----------
  if (tid < 512) {
    float    sk = h4;
    unsigned si = (unsigned)p;
#pragma unroll
    for (int kk = 2; kk <= 64; kk <<= 1) {
#pragma unroll
      for (int j = kk >> 1; j > 0; j >>= 1) {
        const float    pk = __shfl_xor(sk, j, 64);
        const unsigned pi = __shfl_xor(si, j, 64);
        const bool amFirst = (sk > pk) || (sk == pk && si < pi);
        const bool lower   = (lane & j) == 0;
        const bool dir     = (lane & kk) == 0;
        const bool keepMine = (lower == dir) ? amFirst : !amFirst;
        if (!keepMine) { sk = pk; si = pi; }
      }
    }
    keyA[tid] = sk;
    idxA[tid] = si;
  }
  __syncthreads();

  // ---------- 3-round pairwise top-64 merge ----------
  auto merge_round = [&](const float* kin, const unsigned* iin,
                         float* kout, unsigned* iout, int L, int R, int O) {
    float    ak = kin[L * 64 + lane];
    unsigned ai = iin[L * 64 + lane];
    float    bk = kin[R * 64 + 63 - lane];
    unsigned bi = iin[R * 64 + 63 - lane];
    float mk; unsigned mi;
    if ((ak > bk) || (ak == bk && ai < bi)) { mk = ak; mi = ai; }
    else                                    { mk = bk; mi = bi; }
#pragma unroll
    for (int j = 32; j > 0; j >>= 1) {
      const float    pk = __shfl_xor(mk, j, 64);
      const unsigned pi = __shfl_xor(mi, j, 64);
      const bool amF   = (mk > pk) || (mk == pk && mi < pi);
      const bool lower = (lane & j) == 0;
      if (lower != amF) { mk = pk; mi = pi; }
    }
    kout[O * 64 + lane] = mk;
    iout[O * 64 + lane] = mi;
  };
  if (wv < 4) merge_round(keyA, idxA, keyB, idxB, 2 * wv, 2 * wv + 1, wv);
  __syncthreads();
  if (wv < 2) merge_round(keyB, idxB, keyA, idxA, 2 * wv, 2 * wv + 1, wv);
  __syncthreads();
  if (wv == 0) merge_round(keyA, idxA, keyB, idxB, 0, 1, 0);
  __syncthreads();
  // top-64 desc in keyB/idxB[0..63]

  // ---------- gather top-64 into featS [dim][node] (overlays bufA) ----------
  {
    float* featS = stageF + FO_FEAT;
    const int k = tid >> 4, t = tid & 15;
    const int node = (int)idxB[k];
    float vals[7];
#pragma unroll
    for (int m = 0; m < 7; m++) {
      const int d = t + 16 * m;
      float val = 0.f;
      if (d < 32)       val = hs1[gb + (size_t)d * 512 + node];
      else if (d < 64)  val = hs2[gb + (size_t)(d - 32) * 512 + node];
      else if (d < 96)  val = bufA[node * STA + (d - 64)];
      else              val = keyB[k];
      vals[m] = val;
    }
    __syncthreads();   // bufA(h3) reads done before featS overlay writes
#pragma unroll
    for (int m = 0; m < 7; m++) {
      const int d = t + 16 * m;
      if (d < 97) featS[d * 64 + k] = vals[m];
    }
  }
  __syncthreads();

  // ---------- conv1 (per-node linear over 97): wave = 1 channel ----------
  {
    const float* featS = stageF + FO_FEAT;
    float* c1s = stageF + FO_C1;
    const int ch = wv;
    float a = c1b[ch];
    const float* wr = c1w + ch * 97;
    for (int d = 0; d < 97; d++)
      a = fmaf(featS[d * 64 + lane], wr[d], a);
    c1s[ch * 64 + lane] = fmaxf(a, 0.f);
  }
  __syncthreads();

  // ---------- maxpool(2,2) ----------
  if (tid < 512) {
    const float* c1s = stageF + FO_C1;
    float* ps  = stageF + FO_P;
    const int o = tid >> 5, jj = tid & 31;
    ps[o * 32 + jj] = fmaxf(c1s[o * 64 + 2 * jj], c1s[o * 64 + 2 * jj + 1]);
  }
  __syncthreads();

  // ---------- conv2 (k=5, valid): wave = 2 out channels ----------
  {
    const float* ps  = stageF + FO_P;
    float* c2s = stageF + FO_C2;
    const int o = wv;
    if (lane < 28) {
      float a0 = 0.f, a1 = 0.f;
      for (int i = 0; i < 16; i++) {
#pragma unroll
        for (int r = 0; r < 5; r++) {
          const float pv = ps[i * 32 + lane + r];
          a0 = fmaf(pv, c2w[((o     ) * 16 + i) * 5 + r], a0);
          a1 = fmaf(pv, c2w[((o + 16) * 16 + i) * 5 + r], a1);
        }
      }
      c2s[(o     ) * 28 + lane] = fmaxf(a0 + c2b[o     ], 0.f);
      c2s[(o + 16) * 28 + lane] = fmaxf(a1 + c2b[o + 16], 0.f);
    }
  }
  __syncthreads();

  // ---------- d1: 896 -> 128 relu; wave computes 8 outputs ----------
  {
    const float* c2s  = stageF + FO_C2;
    float* hids = stageF + FO_HID;
    float fl[14];
#pragma unroll
    for (int j = 0; j < 14; j++) fl[j] = c2s[lane + j * 64];
    for (int hh = 0; hh < 8; hh++) {
      const int hI = wv * 8 + hh;
      const float* wr = d1w + (size_t)hI * 896;
      float a = 0.f;
#pragma unroll
      for (int j = 0; j < 14; j++) a = fmaf(fl[j], wr[lane + j * 64], a);
#pragma unroll
      for (int m = 32; m > 0; m >>= 1) a += __shfl_xor(a, m, 64);
      if (lane == 0) hids[hI] = fmaxf(a + d1b[hI], 0.f);
    }
  }
  __syncthreads();

  // ---------- d2: 128 -> 10 ----------
  if (tid < 10) {
    const float* hids = stageF + FO_HID;
    const float* wr = d2w + tid * 128;
    float a = d2b[tid];
#pragma unroll 8
    for (int hh = 0; hh < 128; hh++) a = fmaf(hids[hh], wr[hh], a);
    out[g * 10 + tid] = a;
  }
}

extern "C" void kernel_launch(void* const* d_in, const int* in_sizes, int n_in,
                              void* d_out, int out_size, void* d_ws, size_t ws_size,
                              hipStream_t stream) {
  const float* x   = (const float*)d_in[0];
  const float* W0  = (const float*)d_in[1];
  const float* b0  = (const float*)d_in[2];
  const float* W1  = (const float*)d_in[3];
  const float* b1  = (const float*)d_in[4];
  const float* W2  = (const float*)d_in[5];
  const float* b2  = (const float*)d_in[6];
  const float* W3  = (const float*)d_in[7];
  const float* b3  = (const float*)d_in[8];
  const float* c1w = (const float*)d_in[9];
  const float* c1b = (const float*)d_in[10];
  const float* c2w = (const float*)d_in[11];
  const float* c2b = (const float*)d_in[12];
  const float* d1w = (const float*)d_in[13];
  const float* d1b = (const float*)d_in[14];
  const float* d2w = (const float*)d_in[15];
  const float* d2b = (const float*)d_in[16];
  const int* esrc  = (const int*)d_in[17];
  const int* edst  = (const int*)d_in[18];

  float* hs1 = (float*)d_ws;                       // 16 MB
  float* hs2 = hs1 + (size_t)NG * NP * 32;         // +16 MB
  float* outp = (float*)d_out;

  hipFuncSetAttribute(reinterpret_cast<const void*>(dgcnn_fused),
                      hipFuncAttributeMaxDynamicSharedMemorySize, SMEM_SZ);
  dgcnn_fused<<<NG, 1024, SMEM_SZ, stream>>>(x, W0, b0, W1, b1, W2, b2, W3, b3,
                                             c1w, c1b, c2w, c2b, d1w, d1b, d2w, d2b,
                                             esrc, edst, hs1, hs2, outp);
}